// Round 13
// baseline (406.424 us; speedup 1.0000x reference)
//
#include <hip/hip_runtime.h>

// CSTR gated-estimator trajectory cost — 1 lane/sample, quadratic-in-d phi,
// sched_barrier-pinned latency hiding. B=8192, T=2048 sequential steps, N=2.
//
// Model (fits R0/R1/R8/R10/R11): in-order issue; exp2/rcp ~45-50 cyc latency
// exposed at first consumer. R11 regressed because LLVM sank the exp2 to its
// use, serializing both trans latencies AFTER the filler block. This version
// pins placement with __builtin_amdgcn_sched_barrier(0):
//   B1 (pre-d: q,g,t0,cost ~22 ops)   <- hides PREVIOUS exp2 latency
//   y=1+E; d=rcp(y)                    [fence]
//   B2 (uv,pA,pB,pC ~25 ops, d-indep) <- hides rcp latency   [fence]
//   phi = fma(d, fma(d,pC,pB), pA); E = exp2(phi)            [fence]
//   G  (state advance, 9 ops)         <- starts hiding exp2; next B1 finishes
// Dep cycle ~115 cyc; issue ~130 -> predicted ~135-155 cyc/step.
//
// Exact algebra (same liberties as all passing rounds):
//   x' = q + d*g; h' = h + d*dx; q = Ad*x + Hs*x_sw + w + C + kxh;
//   g = Hs*K.dx; kxhC' = kxhC + d*g (exact); half-form phi:
//   phi(z) = sum_i z_i t_i(z) + c0, t affine => phi(z0+d*v) = pA + d*pB + d^2*pC
//   with z0=(q1,q2,h1,h2), v=(g,g,dx1,dx2); all coeffs pre-scaled by -log2(e).
//   E-carry: E0=0 -> y=1 -> d=rcp(1)=1 exact at t=0 (gate forced open; h
//   frozen automatically since dx0=0). Cost moments reconstructed at end.

#define T_STEPS 2048
#define BATCH   8192

__global__ __launch_bounds__(64, 1) void cstr_kernel(
    const float* __restrict__ w,   // (B, 2, T)
    const float* __restrict__ K,   // (1, 2)
    const float* __restrict__ L,   // (4, 4)
    const float* __restrict__ M,   // (1, 4)
    const float* __restrict__ Mo,  // (1, 1)
    float* __restrict__ out)       // (B,)
{
    const int s = blockIdx.x * 64 + (int)threadIdx.x;

    constexpr float Hs = 0.01f;
    constexpr float Ad = 1.0f - 2.0f * Hs;          // 0.98
    constexpr float Rc = 0.1f;
    constexpr float SC = -1.44269504088896340736f;  // -log2(e)

    const float k1 = K[0], k2 = K[1];

    // upper-tri fold of L, pre-scaled into exp2 domain
    const float u11 = L[0] * SC;
    const float u12 = (L[1] + L[4]) * SC;
    const float u13 = (L[2] + L[8]) * SC;
    const float u14 = (L[3] + L[12]) * SC;
    const float u22 = L[5] * SC;
    const float u23 = (L[6] + L[9]) * SC;
    const float u24 = (L[7] + L[13]) * SC;
    const float u33 = L[10] * SC;
    const float u34 = (L[11] + L[14]) * SC;
    const float u44 = L[15] * SC;
    const float u1112 = u11 + u12;
    const float m1s = M[0] * SC, m2s = M[1] * SC, m3s = M[2] * SC, m4s = M[3] * SC;
    const float c0s = Mo[0] * SC;

    const float hk1 = Hs * k1, hk2 = Hs * k2;
    const float C1v = 0.5f * Hs * Hs;               // +H^2/2
    const float C21 = -1.5f * Hs * Hs;              // C2 - C1

    // ---- state ----
    float x1 = 1.0f, x2 = 0.0f;   // x0 = (1, 0)
    float h1 = x1, h2 = x2;
    float dx1 = 0.0f, dx2 = 0.0f;
    float kxhC = hk1 + C1v;       // Hs*K.h + C1 (h0=(1,0) -> K.h0 = k1)
    float E = 0.0f;               // carried exp2(phi); 0 -> d=1 exact at t=0
    float aA1 = 0.0f, aA2 = 0.0f; // Sum x1^2, Sum x2^2
    float aXY = 0.0f;             // Sum x1*x2
    float aD  = 0.0f;             // Sum delta

    auto step = [&](float w1, float w2, bool cost) {
        // ---- B1: d-independent; issues under the PREVIOUS exp2 latency ----
        float b1  = w1 + kxhC;
        float w2c = w2 + C21;
        float b2  = w2c + kxhC;
        float q1  = fmaf(Ad, x1, fmaf(Hs, x2, b1));
        float q2  = fmaf(Ad, x2, fmaf(Hs, x1, b2));
        float g   = fmaf(hk1, dx1, hk2 * dx2);       // Hs*K.(x-h)
        float t01 = fmaf(u11, q1, m1s);
        t01 = fmaf(u12, q2, t01);
        t01 = fmaf(u13, h1, t01);
        t01 = fmaf(u14, h2, t01);
        float t02 = fmaf(u22, q2, m2s);
        t02 = fmaf(u23, h1, t02);
        t02 = fmaf(u24, h2, t02);
        float t03 = fmaf(u33, h1, m3s);
        t03 = fmaf(u34, h2, t03);
        float t04 = fmaf(u44, h2, m4s);
        if (cost) {                   // stage cost uses PRE-update x
            aA1 = fmaf(x1, x1, aA1);
            aA2 = fmaf(x2, x2, aA2);
            aXY = fmaf(x1, x2, aXY);
        }
        __builtin_amdgcn_sched_barrier(0);
        // ---- resolve gate ----
        float y = 1.0f + E;
        float d = __builtin_amdgcn_rcpf(y);          // sigmoid(phi_t)
        __builtin_amdgcn_sched_barrier(0);
        // ---- B2: still d-independent; issues under the rcp latency ----
        float uv1 = fmaf(u1112, g, fmaf(u13, dx1, u14 * dx2));
        float uv2 = fmaf(u22, g, fmaf(u23, dx1, u24 * dx2));
        float uv3 = fmaf(u33, dx1, u34 * dx2);
        float uv4 = u44 * dx2;
        float pA  = fmaf(q1, t01, fmaf(q2, t02, fmaf(h1, t03, fmaf(h2, t04, c0s))));
        float t012 = t01 + t02;
        float pB  = fmaf(g, t012, fmaf(dx1, t03, fmaf(dx2, t04,
                    fmaf(q1, uv1, fmaf(q2, uv2, fmaf(h1, uv3, h2 * uv4))))));
        float uv12 = uv1 + uv2;
        float pC  = fmaf(g, uv12, fmaf(dx1, uv3, dx2 * uv4));
        if (cost) aD += d;            // d ready by end of B2 (no stall)
        __builtin_amdgcn_sched_barrier(0);
        // ---- phi_{t+1} and its exp (pinned here, latency hidden by G+B1) ----
        float phi = fmaf(d, fmaf(d, pC, pB), pA);
        E = __builtin_amdgcn_exp2f(phi);
        __builtin_amdgcn_sched_barrier(0);
        // ---- G: state advance (post-d) — issues under exp2 latency ----
        x1 = fmaf(d, g, q1);
        x2 = fmaf(d, g, q2);
        h1 = fmaf(d, dx1, h1);
        h2 = fmaf(d, dx2, h2);
        kxhC = fmaf(d, g, kxhC);                     // exact incremental
        dx1 = x1 - h1;
        dx2 = x2 - h2;
    };

    // 8-step chunks (2 float4 per stream), double-buffered
    auto chunk = [&](const float4* b0, const float4* b1, bool lastc) {
        #pragma unroll
        for (int q = 0; q < 2; ++q) {
            float4 a = b0[q];
            float4 b = b1[q];
            step(a.x, b.x, true);
            step(a.y, b.y, true);
            step(a.z, b.z, true);
            step(a.w, b.w, !(lastc && (q == 1)));    // t=T-1: no stage cost
        }
    };

    const float4* r0 = reinterpret_cast<const float4*>(w + (size_t)s * 2 * T_STEPS);
    const float4* r1 = reinterpret_cast<const float4*>(w + (size_t)s * 2 * T_STEPS + T_STEPS);

    float4 A0[2], A1[2], B0[2], B1[2];
    #pragma unroll
    for (int q = 0; q < 2; ++q) { A0[q] = r0[q];     A1[q] = r1[q]; }
    #pragma unroll
    for (int q = 0; q < 2; ++q) { B0[q] = r0[2 + q]; B1[q] = r1[2 + q]; }

    chunk(A0, A1, false);                            // chunk 0

    for (int i = 0; i < 127; ++i) {                  // chunks 1..254
        const float4* p0 = r0 + (size_t)(2 + 2 * i) * 2;
        const float4* p1 = r1 + (size_t)(2 + 2 * i) * 2;
        #pragma unroll
        for (int q = 0; q < 2; ++q) { A0[q] = p0[q]; A1[q] = p1[q]; }
        chunk(B0, B1, false);                        // chunk 1+2i
        const float4* q0 = r0 + (size_t)(3 + 2 * i) * 2;
        const float4* q1 = r1 + (size_t)(3 + 2 * i) * 2;
        #pragma unroll
        for (int q = 0; q < 2; ++q) { B0[q] = q0[q]; B1[q] = q1[q]; }
        chunk(A0, A1, false);                        // chunk 2+2i
    }
    chunk(B0, B1, true);                             // chunk 255 (last: no cost)

    // Sum us^2 = k1^2 Sx1^2 + k2^2 Sx2^2 + 2 k1 k2 Sx1x2
    float us2 = fmaf(k1 * k1, aA1, fmaf(k2 * k2, aA2, 2.0f * k1 * k2 * aXY));
    float J = aA1 + aA2 + Rc * us2 + aD
            + 10.0f * fmaf(x1, x1, x2 * x2);         // terminal cost
    out[s] = J;
}

extern "C" void kernel_launch(void* const* d_in, const int* in_sizes, int n_in,
                              void* d_out, int out_size, void* d_ws, size_t ws_size,
                              hipStream_t stream) {
    const float* w  = (const float*)d_in[0];
    const float* K  = (const float*)d_in[1];
    const float* L  = (const float*)d_in[2];
    const float* M  = (const float*)d_in[3];
    const float* Mo = (const float*)d_in[4];
    float* out = (float*)d_out;

    // 8192 samples, 1 lane each = 128 blocks of 64 (1 wave/block)
    hipLaunchKernelGGL(cstr_kernel, dim3(BATCH / 64), dim3(64), 0, stream,
                       w, K, L, M, Mo, out);
}